// Round 3
// baseline (162.046 us; speedup 1.0000x reference)
//
#include <hip/hip_runtime.h>
#include <math.h>

typedef unsigned short u16;
typedef unsigned int u32;
typedef __attribute__((ext_vector_type(4))) float f32x4;
typedef __attribute__((ext_vector_type(8))) short bf16x8;

#define NP 16
#define DLAT 768
#define HDIM 3072
#define NB 256
#define MAXO 250
#define TOT 2800

__device__ __forceinline__ u16 f2b(float f) {
  union { float f; u32 u; } v; v.f = f;
  u32 u = v.u;
  u32 r = (u + 0x7fffu + ((u >> 16) & 1u)) >> 16;
  return (u16)r;
}

__device__ __forceinline__ u32 cvtpk(float lo, float hi) {
  u32 r;
  asm("v_cvt_pk_bf16_f32 %0, %1, %2" : "=v"(r) : "v"(lo), "v"(hi));
  return r;
}

// ---------------- LayerNorm: x[B,P,D] fp32 -> xn[P,B,D] bf16 ----------------
__global__ __launch_bounds__(256) void ln_kernel(
    const float* __restrict__ x, const float* __restrict__ gamma,
    const float* __restrict__ beta, u16* __restrict__ xn) {
  const int wave = threadIdx.x >> 6, lane = threadIdx.x & 63;
  const int row = blockIdx.x * 4 + wave;         // 0..4095 = b*16+p
  const int b = row >> 4, p = row & 15;
  const float4* xr = (const float4*)(x + (size_t)row * DLAT);
  const float4* g4 = (const float4*)(gamma + (size_t)p * DLAT);
  const float4* b4 = (const float4*)(beta + (size_t)p * DLAT);
  float4 v[3];
  float s = 0.f, ss = 0.f;
#pragma unroll
  for (int j = 0; j < 3; ++j) {
    v[j] = xr[lane + j * 64];
    s += v[j].x + v[j].y + v[j].z + v[j].w;
    ss += v[j].x * v[j].x + v[j].y * v[j].y + v[j].z * v[j].z + v[j].w * v[j].w;
  }
#pragma unroll
  for (int o = 32; o; o >>= 1) { s += __shfl_xor(s, o); ss += __shfl_xor(ss, o); }
  const float mu = s * (1.f / 768.f);
  const float var = ss * (1.f / 768.f) - mu * mu;
  const float rstd = rsqrtf(var + 1e-5f);
  u16* xo = xn + ((size_t)(p * NB + b)) * DLAT;
#pragma unroll
  for (int j = 0; j < 3; ++j) {
    const int f = lane + j * 64;
    float4 g = g4[f], be = b4[f];
    float o0 = (v[j].x - mu) * rstd * g.x + be.x;
    float o1 = (v[j].y - mu) * rstd * g.y + be.y;
    float o2 = (v[j].z - mu) * rstd * g.z + be.z;
    float o3 = (v[j].w - mu) * rstd * g.w + be.w;
    uint2 w;
    w.x = (u32)f2b(o0) | ((u32)f2b(o1) << 16);
    w.y = (u32)f2b(o2) | ((u32)f2b(o3) << 16);
    *(uint2*)&xo[f * 4] = w;
  }
}

// ---------------- fc1: h = GELU(xn @ w1^T)  per part ----------------
// No LDS, no staging: MFMA fragments are loaded straight from global (L1/L2)
// into registers, double-buffered one K-step ahead. w1 fp32 -> bf16 via
// v_cvt_pk_bf16_f32 in-register. Bare s_barrier keeps waves lockstep so the
// 4 waves' identical B reads dedup in L1. BM=256 (w1 read once), BN=64.
__global__ __launch_bounds__(256) void fc1_kernel(
    const u16* __restrict__ xn, const float* __restrict__ w1, u16* __restrict__ h) {
  const int bid = blockIdx.x;
  const int p = bid / 48;
  const int n0 = (bid % 48) * 64;
  const int tid = threadIdx.x;
  const int lane = tid & 63, wave = tid >> 6;
  const int lanelo = lane & 15, lanehi = lane >> 4;

  // per-lane fragment base pointers
  const u16* Ap = xn + (size_t)p * NB * DLAT
                  + (size_t)(wave * 64 + lanelo) * DLAT + lanehi * 8;
  const float* Bp = w1 + (size_t)p * HDIM * DLAT
                    + (size_t)(n0 + lanelo) * DLAT + lanehi * 8;

  f32x4 acc[4][4] = {};
  bf16x8 a0[4], a1[4];
  float4 b0[4][2], b1[4][2];

  auto LDA = [&](bf16x8* a, int k) {
#pragma unroll
    for (int m = 0; m < 4; ++m)
      a[m] = *(const bf16x8*)(Ap + (size_t)m * 16 * DLAT + k);
  };
  auto LDB = [&](float4 (*b)[2], int k) {
#pragma unroll
    for (int n = 0; n < 4; ++n) {
      const float* q = Bp + (size_t)n * 16 * DLAT + k;
      b[n][0] = *(const float4*)q;
      b[n][1] = *(const float4*)(q + 4);
    }
  };
  auto FMAS = [&](bf16x8* a, float4 (*b)[2]) {
    bf16x8 fb[4];
#pragma unroll
    for (int n = 0; n < 4; ++n) {
      union { u32 u[4]; bf16x8 v; } t;
      t.u[0] = cvtpk(b[n][0].x, b[n][0].y);
      t.u[1] = cvtpk(b[n][0].z, b[n][0].w);
      t.u[2] = cvtpk(b[n][1].x, b[n][1].y);
      t.u[3] = cvtpk(b[n][1].z, b[n][1].w);
      fb[n] = t.v;
    }
#pragma unroll
    for (int m = 0; m < 4; ++m)
#pragma unroll
      for (int n = 0; n < 4; ++n)
        acc[m][n] = __builtin_amdgcn_mfma_f32_16x16x32_bf16(a[m], fb[n], acc[m][n], 0, 0, 0);
  };

  LDA(a0, 0);
  LDB(b0, 0);
  const int NK = DLAT / 32;  // 24 (even)
  for (int kt = 0; kt < NK; kt += 2) {
    LDA(a1, (kt + 1) * 32);
    LDB(b1, (kt + 1) * 32);
    __builtin_amdgcn_s_barrier();   // bare barrier: lockstep for L1 dedup
    FMAS(a0, b0);
    if (kt + 2 < NK) {
      LDA(a0, (kt + 2) * 32);
      LDB(b0, (kt + 2) * 32);
    }
    __builtin_amdgcn_s_barrier();
    FMAS(a1, b1);
  }

  // epilogue: exact GELU, store bf16
  u16* hp = h + (size_t)p * NB * HDIM;
#pragma unroll
  for (int m = 0; m < 4; ++m) {
#pragma unroll
    for (int n = 0; n < 4; ++n) {
      const int col = n0 + n * 16 + lanelo;
#pragma unroll
      for (int r = 0; r < 4; ++r) {
        const int row = wave * 64 + m * 16 + lanehi * 4 + r;
        const float vv = acc[m][n][r];
        const float gel = 0.5f * vv * (1.f + erff(vv * 0.70710678118654752f));
        hp[(size_t)row * HDIM + col] = f2b(gel);
      }
    }
  }
}

// ---------------- fc2: out = h @ w2^T + b2, concat slices ----------------
// BM=64, BN=64, BK=32; 4 waves 2x2, each 32x32. (unchanged from round 2 — ~4us)
__global__ __launch_bounds__(256) void fc2_kernel(
    const u16* __restrict__ hbuf, const float* __restrict__ w2,
    const float* __restrict__ b2, float* __restrict__ out) {
  const int bid = blockIdx.x;
  const int bs = (bid & 7) * 32 + (bid >> 3);    // XCD swizzle (256 = 8*32)
  const int p = bs >> 4;
  const int mb = (bs >> 2) & 3;
  const int nb = bs & 3;
  const int odim = 100 + 10 * p;
  const int n0 = nb * 64;
  if (n0 >= odim) return;                        // uniform per block
  const int m0 = mb * 64;
  const int off = 100 * p + 5 * p * (p - 1);

  const int tid = threadIdx.x;
  const int lane = tid & 63, wave = tid >> 6;
  const int lanelo = lane & 15, lanehi = lane >> 4;
  const int wr = wave >> 1, wc = wave & 1;

  const u16* Ap = hbuf + (size_t)p * NB * HDIM + (size_t)m0 * HDIM;
  const float* Bp = w2 + (size_t)p * MAXO * HDIM;

  __shared__ u16 As[3][64 * 32];   // 12 KiB
  __shared__ u16 Bs[2][64 * 32];   // 8 KiB

  int ag_off;
  const int ag_base = (64 * wave) * 8;
  {
    int slot = 64 * wave + lane;
    int r = slot >> 2;
    int c = (slot & 3) ^ ((r >> 1) & 3);
    ag_off = r * HDIM + c * 8;
  }
  const int br0 = min(n0 + (tid >> 3), MAXO - 1);
  const int br1 = min(n0 + (tid >> 3) + 32, MAXO - 1);
  const float* bg0 = Bp + (size_t)br0 * HDIM + (tid & 7) * 4;
  const float* bg1 = Bp + (size_t)br1 * HDIM + (tid & 7) * 4;
  int bso[2];
#pragma unroll
  for (int i = 0; i < 2; ++i) {
    int r = (tid >> 3) + 32 * i;
    int c = ((tid & 7) >> 1) ^ ((r >> 1) & 3);
    bso[i] = (r * 4 + c) * 8 + (tid & 1) * 4;
  }
  int a_sl[2], b_sl[2];
#pragma unroll
  for (int m = 0; m < 2; ++m) {
    int r = wr * 32 + m * 16 + lanelo;
    a_sl[m] = (r * 4 + (lanehi ^ ((r >> 1) & 3))) * 8;
    int rb = wc * 32 + m * 16 + lanelo;
    b_sl[m] = (rb * 4 + (lanehi ^ ((rb >> 1) & 3))) * 8;
  }

  f32x4 acc[2][2] = {};
  float4 bA0, bA1, bB0, bB1;
  const int NK = HDIM / 32;  // 96

  auto gll16 = [](const void* g, void* l) {
    __builtin_amdgcn_global_load_lds(
        (const __attribute__((address_space(1))) void*)g,
        (__attribute__((address_space(3))) void*)l, 16, 0, 0);
  };

  auto issue = [&](int kt, float4& r0, float4& r1) {
    const int k2 = kt * 32;
    gll16(Ap + ag_off + k2, &As[kt % 3][ag_base]);
    asm volatile("" ::: "memory");
    r0 = *(const float4*)(bg0 + k2);
    r1 = *(const float4*)(bg1 + k2);
    asm volatile("" ::: "memory");
  };

  auto step = [&](int kt, float4& r0, float4& r1) {
    if (kt + 1 < NK) asm volatile("s_waitcnt vmcnt(3)" ::: "memory");
    else             asm volatile("s_waitcnt vmcnt(0)" ::: "memory");
    {
      u16* bb = &Bs[kt & 1][0];
      uint2 w0, w1v;
      w0.x = (u32)f2b(r0.x) | ((u32)f2b(r0.y) << 16);
      w0.y = (u32)f2b(r0.z) | ((u32)f2b(r0.w) << 16);
      w1v.x = (u32)f2b(r1.x) | ((u32)f2b(r1.y) << 16);
      w1v.y = (u32)f2b(r1.z) | ((u32)f2b(r1.w) << 16);
      *(uint2*)&bb[bso[0]] = w0;
      *(uint2*)&bb[bso[1]] = w1v;
    }
    asm volatile("s_waitcnt lgkmcnt(0)" ::: "memory");
    __builtin_amdgcn_s_barrier();
    asm volatile("" ::: "memory");
    if (kt + 2 < NK) issue(kt + 2, r0, r1);
    const u16* a_ = &As[kt % 3][0];
    const u16* b_ = &Bs[kt & 1][0];
    bf16x8 af[2], bf[2];
#pragma unroll
    for (int m = 0; m < 2; ++m) af[m] = *(const bf16x8*)&a_[a_sl[m]];
#pragma unroll
    for (int n = 0; n < 2; ++n) bf[n] = *(const bf16x8*)&b_[b_sl[n]];
#pragma unroll
    for (int m = 0; m < 2; ++m)
#pragma unroll
      for (int n = 0; n < 2; ++n)
        acc[m][n] = __builtin_amdgcn_mfma_f32_16x16x32_bf16(af[m], bf[n], acc[m][n], 0, 0, 0);
  };

  issue(0, bA0, bA1);
  issue(1, bB0, bB1);
  for (int kt = 0; kt < NK; kt += 2) {
    step(kt, bA0, bA1);
    step(kt + 1, bB0, bB1);
  }

#pragma unroll
  for (int m = 0; m < 2; ++m) {
#pragma unroll
    for (int n = 0; n < 2; ++n) {
      const int col = n0 + wc * 32 + n * 16 + lanelo;
      if (col < odim) {
        const float bias = b2[(size_t)p * MAXO + col];
#pragma unroll
        for (int r = 0; r < 4; ++r) {
          const int row = m0 + wr * 32 + m * 16 + lanehi * 4 + r;
          out[(size_t)row * TOT + off + col] = acc[m][n][r] + bias;
        }
      }
    }
  }
}

extern "C" void kernel_launch(void* const* d_in, const int* in_sizes, int n_in,
                              void* d_out, int out_size, void* d_ws, size_t ws_size,
                              hipStream_t stream) {
  const float* x = (const float*)d_in[0];
  const float* gamma = (const float*)d_in[1];
  const float* beta = (const float*)d_in[2];
  const float* w1 = (const float*)d_in[3];
  const float* w2 = (const float*)d_in[4];
  const float* b2 = (const float*)d_in[5];
  float* out = (float*)d_out;

  u16* xn = (u16*)d_ws;                             // [16][256][768] bf16
  u16* h = (u16*)d_ws + (size_t)NP * NB * DLAT;     // [16][256][3072] bf16

  ln_kernel<<<1024, 256, 0, stream>>>(x, gamma, beta, xn);
  fc1_kernel<<<NP * 48, 256, 0, stream>>>(xn, w1, h);
  fc2_kernel<<<NP * 16, 256, 0, stream>>>(h, w2, b2, out);
}

// Round 4
// 127.613 us; speedup vs baseline: 1.2698x; 1.2698x over previous
//
#include <hip/hip_runtime.h>
#include <math.h>

typedef unsigned short u16;
typedef unsigned int u32;
typedef __attribute__((ext_vector_type(4))) float f32x4;
typedef __attribute__((ext_vector_type(8))) short bf16x8;

#define NP 16
#define DLAT 768
#define HDIM 3072
#define NB 256
#define MAXO 250
#define TOT 2800

__device__ __forceinline__ u16 f2b(float f) {
  union { float f; u32 u; } v; v.f = f;
  u32 u = v.u;
  u32 r = (u + 0x7fffu + ((u >> 16) & 1u)) >> 16;
  return (u16)r;
}

__device__ __forceinline__ void gll16(const void* g, void* l) {
  __builtin_amdgcn_global_load_lds(
      (const __attribute__((address_space(1))) void*)g,
      (__attribute__((address_space(3))) void*)l, 16, 0, 0);
}

// ---------------- LayerNorm: x[B,P,D] fp32 -> xn[P,B,D] bf16 ----------------
__global__ __launch_bounds__(256) void ln_kernel(
    const float* __restrict__ x, const float* __restrict__ gamma,
    const float* __restrict__ beta, u16* __restrict__ xn) {
  const int wave = threadIdx.x >> 6, lane = threadIdx.x & 63;
  const int row = blockIdx.x * 4 + wave;         // 0..4095 = b*16+p
  const int b = row >> 4, p = row & 15;
  const float4* xr = (const float4*)(x + (size_t)row * DLAT);
  const float4* g4 = (const float4*)(gamma + (size_t)p * DLAT);
  const float4* b4 = (const float4*)(beta + (size_t)p * DLAT);
  float4 v[3];
  float s = 0.f, ss = 0.f;
#pragma unroll
  for (int j = 0; j < 3; ++j) {
    v[j] = xr[lane + j * 64];
    s += v[j].x + v[j].y + v[j].z + v[j].w;
    ss += v[j].x * v[j].x + v[j].y * v[j].y + v[j].z * v[j].z + v[j].w * v[j].w;
  }
#pragma unroll
  for (int o = 32; o; o >>= 1) { s += __shfl_xor(s, o); ss += __shfl_xor(ss, o); }
  const float mu = s * (1.f / 768.f);
  const float var = ss * (1.f / 768.f) - mu * mu;
  const float rstd = rsqrtf(var + 1e-5f);
  u16* xo = xn + ((size_t)(p * NB + b)) * DLAT;
#pragma unroll
  for (int j = 0; j < 3; ++j) {
    const int f = lane + j * 64;
    float4 g = g4[f], be = b4[f];
    float o0 = (v[j].x - mu) * rstd * g.x + be.x;
    float o1 = (v[j].y - mu) * rstd * g.y + be.y;
    float o2 = (v[j].z - mu) * rstd * g.z + be.z;
    float o3 = (v[j].w - mu) * rstd * g.w + be.w;
    uint2 w;
    w.x = (u32)f2b(o0) | ((u32)f2b(o1) << 16);
    w.y = (u32)f2b(o2) | ((u32)f2b(o3) << 16);
    *(uint2*)&xo[f * 4] = w;
  }
}

// ---------------- fc1: h = GELU(xn @ w1^T)  per part ----------------
// fc2-clone structure (the validated one): BM=64, BN=64, BK=32, 4 waves 2x2.
// A via 1 global_load_lds/step, B (fp32) reg-staged -> bf16 -> ds_write.
// Prefetch depth 4 (ring As[5]); steady-state s_waitcnt vmcnt(9), tail 6/3/0.
// XCD swizzle co-locates the 4 mb-siblings of each (p,nb) on one XCD so the
// shared w1 slice is fetched from HBM once and L2-hit 3x.
__global__ __launch_bounds__(256) void fc1_kernel(
    const u16* __restrict__ xn, const float* __restrict__ w1, u16* __restrict__ h) {
  // 3072 blocks: xcd = bid&7 owns 96 (p,nb)-groups; 4 mb-siblings adjacent.
  const int bid = blockIdx.x;
  const int xcd = bid & 7;
  const int q = bid >> 3;              // 0..383 within XCD
  const int g = xcd * 96 + (q >> 2);   // (p,nb) group 0..767
  const int mb = q & 3;
  const int p = g / 48;
  const int nb = g % 48;
  const int m0 = mb * 64, n0 = nb * 64;

  const int tid = threadIdx.x;
  const int lane = tid & 63, wave = tid >> 6;
  const int lanelo = lane & 15, lanehi = lane >> 4;
  const int wr = wave >> 1, wc = wave & 1;

  const u16* Ap = xn + (size_t)p * NB * DLAT + (size_t)m0 * DLAT;
  const float* Bp = w1 + (size_t)p * HDIM * DLAT + (size_t)n0 * DLAT;

  __shared__ u16 As[5][64 * 32];   // 20 KiB ring
  __shared__ u16 Bs[2][64 * 32];   // 8 KiB

  // gll A: per-lane swizzled global source, wave-uniform LDS base
  int ag_off;
  const int ag_base = (64 * wave) * 8;
  {
    int slot = 64 * wave + lane;
    int r = slot >> 2;
    int c = (slot & 3) ^ ((r >> 1) & 3);
    ag_off = r * DLAT + c * 8;
  }
  // B global (fp32): 2 rows/thread/step
  const float* bg0 = Bp + (size_t)(tid >> 3) * DLAT + (tid & 7) * 4;
  const float* bg1 = bg0 + (size_t)32 * DLAT;
  int bso[2];
#pragma unroll
  for (int i = 0; i < 2; ++i) {
    int r = (tid >> 3) + 32 * i;
    int c = ((tid & 7) >> 1) ^ ((r >> 1) & 3);
    bso[i] = (r * 4 + c) * 8 + (tid & 1) * 4;
  }
  int a_sl[2], b_sl[2];
#pragma unroll
  for (int m = 0; m < 2; ++m) {
    int r = wr * 32 + m * 16 + lanelo;
    a_sl[m] = (r * 4 + (lanehi ^ ((r >> 1) & 3))) * 8;
    int rb = wc * 32 + m * 16 + lanelo;
    b_sl[m] = (rb * 4 + (lanehi ^ ((rb >> 1) & 3))) * 8;
  }

  f32x4 acc[2][2] = {};
  float4 rB[4][2];
  const int NK = DLAT / 32;  // 24

  auto issue = [&](int kt) {
    const int k2 = kt * 32;
    gll16(Ap + ag_off + k2, &As[kt % 5][ag_base]);
    asm volatile("" ::: "memory");
    rB[kt & 3][0] = *(const float4*)(bg0 + k2);
    rB[kt & 3][1] = *(const float4*)(bg1 + k2);
    asm volatile("" ::: "memory");
  };

  auto step = [&](int kt, int wn) {
    if (wn == 9)      asm volatile("s_waitcnt vmcnt(9)" ::: "memory");
    else if (wn == 6) asm volatile("s_waitcnt vmcnt(6)" ::: "memory");
    else if (wn == 3) asm volatile("s_waitcnt vmcnt(3)" ::: "memory");
    else              asm volatile("s_waitcnt vmcnt(0)" ::: "memory");
    {
      u16* bb = &Bs[kt & 1][0];
      const float4 r0 = rB[kt & 3][0], r1 = rB[kt & 3][1];
      uint2 w0, w1v;
      w0.x = (u32)f2b(r0.x) | ((u32)f2b(r0.y) << 16);
      w0.y = (u32)f2b(r0.z) | ((u32)f2b(r0.w) << 16);
      w1v.x = (u32)f2b(r1.x) | ((u32)f2b(r1.y) << 16);
      w1v.y = (u32)f2b(r1.z) | ((u32)f2b(r1.w) << 16);
      *(uint2*)&bb[bso[0]] = w0;
      *(uint2*)&bb[bso[1]] = w1v;
    }
    asm volatile("s_waitcnt lgkmcnt(0)" ::: "memory");
    __builtin_amdgcn_s_barrier();
    asm volatile("" ::: "memory");
    if (kt + 4 < NK) issue(kt + 4);
    const u16* a_ = &As[kt % 5][0];
    const u16* b_ = &Bs[kt & 1][0];
    bf16x8 af[2], bf[2];
#pragma unroll
    for (int m = 0; m < 2; ++m) af[m] = *(const bf16x8*)&a_[a_sl[m]];
#pragma unroll
    for (int n = 0; n < 2; ++n) bf[n] = *(const bf16x8*)&b_[b_sl[n]];
#pragma unroll
    for (int m = 0; m < 2; ++m)
#pragma unroll
      for (int n = 0; n < 2; ++n)
        acc[m][n] = __builtin_amdgcn_mfma_f32_16x16x32_bf16(af[m], bf[n], acc[m][n], 0, 0, 0);
  };

  issue(0); issue(1); issue(2); issue(3);
#pragma unroll
  for (int kt = 0; kt < NK - 3; ++kt) step(kt, 9);
  step(NK - 3, 6);
  step(NK - 2, 3);
  step(NK - 1, 0);

  // epilogue: exact GELU, store bf16
  u16* hp = h + (size_t)p * NB * HDIM;
#pragma unroll
  for (int m = 0; m < 2; ++m) {
#pragma unroll
    for (int n = 0; n < 2; ++n) {
      const int col = n0 + wc * 32 + n * 16 + lanelo;
#pragma unroll
      for (int r = 0; r < 4; ++r) {
        const int row = m0 + wr * 32 + m * 16 + lanehi * 4 + r;
        const float vv = acc[m][n][r];
        const float gel = 0.5f * vv * (1.f + erff(vv * 0.70710678118654752f));
        hp[(size_t)row * HDIM + col] = f2b(gel);
      }
    }
  }
}

// ---------------- fc2: out = h @ w2^T + b2, concat slices ----------------
// BM=64, BN=64, BK=32; 4 waves 2x2, each 32x32. (validated at ~memory floor)
__global__ __launch_bounds__(256) void fc2_kernel(
    const u16* __restrict__ hbuf, const float* __restrict__ w2,
    const float* __restrict__ b2, float* __restrict__ out) {
  const int bid = blockIdx.x;
  const int bs = (bid & 7) * 32 + (bid >> 3);    // XCD swizzle (256 = 8*32)
  const int p = bs >> 4;
  const int mb = (bs >> 2) & 3;
  const int nb = bs & 3;
  const int odim = 100 + 10 * p;
  const int n0 = nb * 64;
  if (n0 >= odim) return;                        // uniform per block
  const int m0 = mb * 64;
  const int off = 100 * p + 5 * p * (p - 1);

  const int tid = threadIdx.x;
  const int lane = tid & 63, wave = tid >> 6;
  const int lanelo = lane & 15, lanehi = lane >> 4;
  const int wr = wave >> 1, wc = wave & 1;

  const u16* Ap = hbuf + (size_t)p * NB * HDIM + (size_t)m0 * HDIM;
  const float* Bp = w2 + (size_t)p * MAXO * HDIM;

  __shared__ u16 As[3][64 * 32];   // 12 KiB
  __shared__ u16 Bs[2][64 * 32];   // 8 KiB

  int ag_off;
  const int ag_base = (64 * wave) * 8;
  {
    int slot = 64 * wave + lane;
    int r = slot >> 2;
    int c = (slot & 3) ^ ((r >> 1) & 3);
    ag_off = r * HDIM + c * 8;
  }
  const int br0 = min(n0 + (tid >> 3), MAXO - 1);
  const int br1 = min(n0 + (tid >> 3) + 32, MAXO - 1);
  const float* bg0 = Bp + (size_t)br0 * HDIM + (tid & 7) * 4;
  const float* bg1 = Bp + (size_t)br1 * HDIM + (tid & 7) * 4;
  int bso[2];
#pragma unroll
  for (int i = 0; i < 2; ++i) {
    int r = (tid >> 3) + 32 * i;
    int c = ((tid & 7) >> 1) ^ ((r >> 1) & 3);
    bso[i] = (r * 4 + c) * 8 + (tid & 1) * 4;
  }
  int a_sl[2], b_sl[2];
#pragma unroll
  for (int m = 0; m < 2; ++m) {
    int r = wr * 32 + m * 16 + lanelo;
    a_sl[m] = (r * 4 + (lanehi ^ ((r >> 1) & 3))) * 8;
    int rb = wc * 32 + m * 16 + lanelo;
    b_sl[m] = (rb * 4 + (lanehi ^ ((rb >> 1) & 3))) * 8;
  }

  f32x4 acc[2][2] = {};
  float4 bA0, bA1, bB0, bB1;
  const int NK = HDIM / 32;  // 96

  auto issue = [&](int kt, float4& r0, float4& r1) {
    const int k2 = kt * 32;
    gll16(Ap + ag_off + k2, &As[kt % 3][ag_base]);
    asm volatile("" ::: "memory");
    r0 = *(const float4*)(bg0 + k2);
    r1 = *(const float4*)(bg1 + k2);
    asm volatile("" ::: "memory");
  };

  auto step = [&](int kt, float4& r0, float4& r1) {
    if (kt + 1 < NK) asm volatile("s_waitcnt vmcnt(3)" ::: "memory");
    else             asm volatile("s_waitcnt vmcnt(0)" ::: "memory");
    {
      u16* bb = &Bs[kt & 1][0];
      uint2 w0, w1v;
      w0.x = (u32)f2b(r0.x) | ((u32)f2b(r0.y) << 16);
      w0.y = (u32)f2b(r0.z) | ((u32)f2b(r0.w) << 16);
      w1v.x = (u32)f2b(r1.x) | ((u32)f2b(r1.y) << 16);
      w1v.y = (u32)f2b(r1.z) | ((u32)f2b(r1.w) << 16);
      *(uint2*)&bb[bso[0]] = w0;
      *(uint2*)&bb[bso[1]] = w1v;
    }
    asm volatile("s_waitcnt lgkmcnt(0)" ::: "memory");
    __builtin_amdgcn_s_barrier();
    asm volatile("" ::: "memory");
    if (kt + 2 < NK) issue(kt + 2, r0, r1);
    const u16* a_ = &As[kt % 3][0];
    const u16* b_ = &Bs[kt & 1][0];
    bf16x8 af[2], bf[2];
#pragma unroll
    for (int m = 0; m < 2; ++m) af[m] = *(const bf16x8*)&a_[a_sl[m]];
#pragma unroll
    for (int n = 0; n < 2; ++n) bf[n] = *(const bf16x8*)&b_[b_sl[n]];
#pragma unroll
    for (int m = 0; m < 2; ++m)
#pragma unroll
      for (int n = 0; n < 2; ++n)
        acc[m][n] = __builtin_amdgcn_mfma_f32_16x16x32_bf16(af[m], bf[n], acc[m][n], 0, 0, 0);
  };

  issue(0, bA0, bA1);
  issue(1, bB0, bB1);
  for (int kt = 0; kt < NK; kt += 2) {
    step(kt, bA0, bA1);
    step(kt + 1, bB0, bB1);
  }

#pragma unroll
  for (int m = 0; m < 2; ++m) {
#pragma unroll
    for (int n = 0; n < 2; ++n) {
      const int col = n0 + wc * 32 + n * 16 + lanelo;
      if (col < odim) {
        const float bias = b2[(size_t)p * MAXO + col];
#pragma unroll
        for (int r = 0; r < 4; ++r) {
          const int row = m0 + wr * 32 + m * 16 + lanehi * 4 + r;
          out[(size_t)row * TOT + off + col] = acc[m][n][r] + bias;
        }
      }
    }
  }
}

extern "C" void kernel_launch(void* const* d_in, const int* in_sizes, int n_in,
                              void* d_out, int out_size, void* d_ws, size_t ws_size,
                              hipStream_t stream) {
  const float* x = (const float*)d_in[0];
  const float* gamma = (const float*)d_in[1];
  const float* beta = (const float*)d_in[2];
  const float* w1 = (const float*)d_in[3];
  const float* w2 = (const float*)d_in[4];
  const float* b2 = (const float*)d_in[5];
  float* out = (float*)d_out;

  u16* xn = (u16*)d_ws;                             // [16][256][768] bf16
  u16* h = (u16*)d_ws + (size_t)NP * NB * DLAT;     // [16][256][3072] bf16

  ln_kernel<<<1024, 256, 0, stream>>>(x, gamma, beta, xn);
  fc1_kernel<<<NP * 48 * 4, 256, 0, stream>>>(xn, w1, h);
  fc2_kernel<<<NP * 16, 256, 0, stream>>>(h, w2, b2, out);
}

// Round 5
// 102.718 us; speedup vs baseline: 1.5776x; 1.2424x over previous
//
#include <hip/hip_runtime.h>
#include <math.h>

typedef unsigned short u16;
typedef unsigned int u32;
typedef __attribute__((ext_vector_type(4))) float f32x4;
typedef __attribute__((ext_vector_type(8))) short bf16x8;

#define NP 16
#define DLAT 768
#define HDIM 3072
#define NB 256
#define MAXO 250
#define TOT 2800

__device__ __forceinline__ u16 f2b(float f) {
  union { float f; u32 u; } v; v.f = f;
  u32 u = v.u;
  u32 r = (u + 0x7fffu + ((u >> 16) & 1u)) >> 16;
  return (u16)r;
}

__device__ __forceinline__ u32 cvtpk(float lo, float hi) {
  u32 r;
  asm("v_cvt_pk_bf16_f32 %0, %1, %2" : "=v"(r) : "v"(lo), "v"(hi));
  return r;
}

__device__ __forceinline__ void gll16(const void* g, void* l) {
  __builtin_amdgcn_global_load_lds(
      (const __attribute__((address_space(1))) void*)g,
      (__attribute__((address_space(3))) void*)l, 16, 0, 0);
}

// ---------------- LayerNorm: x[B,P,D] fp32 -> xn[P,B,D] bf16 ----------------
__global__ __launch_bounds__(256) void ln_kernel(
    const float* __restrict__ x, const float* __restrict__ gamma,
    const float* __restrict__ beta, u16* __restrict__ xn) {
  const int wave = threadIdx.x >> 6, lane = threadIdx.x & 63;
  const int row = blockIdx.x * 4 + wave;         // 0..4095 = b*16+p
  const int b = row >> 4, p = row & 15;
  const float4* xr = (const float4*)(x + (size_t)row * DLAT);
  const float4* g4 = (const float4*)(gamma + (size_t)p * DLAT);
  const float4* b4 = (const float4*)(beta + (size_t)p * DLAT);
  float4 v[3];
  float s = 0.f, ss = 0.f;
#pragma unroll
  for (int j = 0; j < 3; ++j) {
    v[j] = xr[lane + j * 64];
    s += v[j].x + v[j].y + v[j].z + v[j].w;
    ss += v[j].x * v[j].x + v[j].y * v[j].y + v[j].z * v[j].z + v[j].w * v[j].w;
  }
#pragma unroll
  for (int o = 32; o; o >>= 1) { s += __shfl_xor(s, o); ss += __shfl_xor(ss, o); }
  const float mu = s * (1.f / 768.f);
  const float var = ss * (1.f / 768.f) - mu * mu;
  const float rstd = rsqrtf(var + 1e-5f);
  u16* xo = xn + ((size_t)(p * NB + b)) * DLAT;
#pragma unroll
  for (int j = 0; j < 3; ++j) {
    const int f = lane + j * 64;
    float4 g = g4[f], be = b4[f];
    float o0 = (v[j].x - mu) * rstd * g.x + be.x;
    float o1 = (v[j].y - mu) * rstd * g.y + be.y;
    float o2 = (v[j].z - mu) * rstd * g.z + be.z;
    float o3 = (v[j].w - mu) * rstd * g.w + be.w;
    uint2 w;
    w.x = (u32)f2b(o0) | ((u32)f2b(o1) << 16);
    w.y = (u32)f2b(o2) | ((u32)f2b(o3) << 16);
    *(uint2*)&xo[f * 4] = w;
  }
}

// ---------------- fc1: h = GELU(xn @ w1^T)  per part ----------------
// m97-structure clone: 128x128 tile, BK=32, 4 waves 2x2 (each 64x64, acc[4][4],
// 16 MFMA/wave/step). A (xn bf16) via global_load_lds w=16, source pre-swizzled
// so LDS stays linear; B (w1 fp32) reg-staged -> v_cvt_pk_bf16_f32 -> swizzled
// ds_write. One __syncthreads per K-step (m97's validated pattern).
// XCD swizzle: the two M-siblings of each (p,n0) are adjacent on one XCD so
// the w1 N-slice is HBM-fetched once, L2-hit the second time.
__global__ __launch_bounds__(256) void fc1_kernel(
    const u16* __restrict__ xn, const float* __restrict__ w1, u16* __restrict__ h) {
  const int bid = blockIdx.x;              // 768 blocks
  const int xcd = bid & 7;
  const int j = bid >> 3;                  // 0..95 within XCD
  const int p = xcd * 2 + (j >= 48 ? 1 : 0);
  const int jj = j % 48;                   // 24 n-tiles x 2 m-tiles
  const int n0 = (jj >> 1) * 128;
  const int m0 = (jj & 1) * 128;

  const int tid = threadIdx.x;
  const int lane = tid & 63, wave = tid >> 6;
  const int lanelo = lane & 15, lanehi = lane >> 4;
  const int wr = wave >> 1, wc = wave & 1;

  const u16* Ap = xn + (size_t)p * NB * DLAT + (size_t)m0 * DLAT;
  const float* Bp = w1 + (size_t)p * HDIM * DLAT + (size_t)n0 * DLAT;

  __shared__ u16 As[2][128 * 32];   // 8 KiB each; [row][32k], 16B slot-swizzled
  __shared__ u16 Bs[2][128 * 32];   // 8 KiB each

  // A gll: 2 chunks/thread. Physical slot s=(r, c) holds global k-group c^(r&3).
  int ag_src[2], ag_dst[2];
#pragma unroll
  for (int i = 0; i < 2; ++i) {
    const int s = wave * 64 + i * 256 + lane;
    const int r = s >> 2;
    const int g = (s & 3) ^ (r & 3);
    ag_src[i] = r * DLAT + g * 8;                 // elements
    ag_dst[i] = (wave * 64 + i * 256) * 8;        // wave-uniform base (elems)
  }
  // B stage: thread owns row rb = tid>>1 (local 0..127), 16 k-elems at kc
  const int rb = tid >> 1;
  const int kc = (tid & 1) * 16;
  const float* bg = Bp + (size_t)rb * DLAT + kc;
  int bw_off[2];
#pragma unroll
  for (int i = 0; i < 2; ++i) {
    const int g = (tid & 1) * 2 + i;              // global k-group 0..3
    bw_off[i] = (rb * 4 + (g ^ (rb & 3))) * 8;
  }
  // fragment read offsets
  int a_sl[4], b_sl[4];
#pragma unroll
  for (int m = 0; m < 4; ++m) {
    const int ra = wr * 64 + m * 16 + lanelo;
    a_sl[m] = (ra * 4 + (lanehi ^ (ra & 3))) * 8;
    const int rbl = wc * 64 + m * 16 + lanelo;
    b_sl[m] = (rbl * 4 + (lanehi ^ (rbl & 3))) * 8;
  }

  f32x4 acc[4][4] = {};
  float4 br[4];
  const int NK = DLAT / 32;  // 24

  auto issueA = [&](int kt) {
    const int k2 = kt * 32;
#pragma unroll
    for (int i = 0; i < 2; ++i)
      gll16(Ap + ag_src[i] + k2, &As[kt & 1][ag_dst[i]]);
  };
  auto loadB = [&](int kt) {
    const float* q = bg + kt * 32;
#pragma unroll
    for (int i = 0; i < 4; ++i) br[i] = *(const float4*)(q + i * 4);
  };
  auto writeB = [&](int kt) {
    u16* bb = &Bs[kt & 1][0];
    uint4 w0, w1v;
    w0.x = cvtpk(br[0].x, br[0].y); w0.y = cvtpk(br[0].z, br[0].w);
    w0.z = cvtpk(br[1].x, br[1].y); w0.w = cvtpk(br[1].z, br[1].w);
    w1v.x = cvtpk(br[2].x, br[2].y); w1v.y = cvtpk(br[2].z, br[2].w);
    w1v.z = cvtpk(br[3].x, br[3].y); w1v.w = cvtpk(br[3].z, br[3].w);
    *(uint4*)&bb[bw_off[0]] = w0;
    *(uint4*)&bb[bw_off[1]] = w1v;
  };

  issueA(0); loadB(0); writeB(0);
  __syncthreads();
#pragma unroll 2
  for (int kt = 0; kt < NK; ++kt) {
    const int cur = kt & 1;
    if (kt + 1 < NK) { issueA(kt + 1); loadB(kt + 1); }
    bf16x8 af[4], bf[4];
    const u16* a_ = &As[cur][0];
    const u16* b_ = &Bs[cur][0];
#pragma unroll
    for (int m = 0; m < 4; ++m) af[m] = *(const bf16x8*)&a_[a_sl[m]];
#pragma unroll
    for (int n = 0; n < 4; ++n) bf[n] = *(const bf16x8*)&b_[b_sl[n]];
#pragma unroll
    for (int m = 0; m < 4; ++m)
#pragma unroll
      for (int n = 0; n < 4; ++n)
        acc[m][n] = __builtin_amdgcn_mfma_f32_16x16x32_bf16(af[m], bf[n], acc[m][n], 0, 0, 0);
    if (kt + 1 < NK) writeB(kt + 1);
    __syncthreads();
  }

  // epilogue: exact GELU, store bf16
  u16* hp = h + (size_t)p * NB * HDIM;
#pragma unroll
  for (int m = 0; m < 4; ++m) {
#pragma unroll
    for (int n = 0; n < 4; ++n) {
      const int col = n0 + wc * 64 + n * 16 + lanelo;
#pragma unroll
      for (int r = 0; r < 4; ++r) {
        const int row = m0 + wr * 64 + m * 16 + lanehi * 4 + r;
        const float vv = acc[m][n][r];
        const float gel = 0.5f * vv * (1.f + erff(vv * 0.70710678118654752f));
        hp[(size_t)row * HDIM + col] = f2b(gel);
      }
    }
  }
}

// ---------------- fc2: out = h @ w2^T + b2, concat slices ----------------
// BM=64, BN=64, BK=32; 4 waves 2x2, each 32x32. (validated at ~memory floor)
__global__ __launch_bounds__(256) void fc2_kernel(
    const u16* __restrict__ hbuf, const float* __restrict__ w2,
    const float* __restrict__ b2, float* __restrict__ out) {
  const int bid = blockIdx.x;
  const int bs = (bid & 7) * 32 + (bid >> 3);    // XCD swizzle (256 = 8*32)
  const int p = bs >> 4;
  const int mb = (bs >> 2) & 3;
  const int nb = bs & 3;
  const int odim = 100 + 10 * p;
  const int n0 = nb * 64;
  if (n0 >= odim) return;                        // uniform per block
  const int m0 = mb * 64;
  const int off = 100 * p + 5 * p * (p - 1);

  const int tid = threadIdx.x;
  const int lane = tid & 63, wave = tid >> 6;
  const int lanelo = lane & 15, lanehi = lane >> 4;
  const int wr = wave >> 1, wc = wave & 1;

  const u16* Ap = hbuf + (size_t)p * NB * HDIM + (size_t)m0 * HDIM;
  const float* Bp = w2 + (size_t)p * MAXO * HDIM;

  __shared__ u16 As[3][64 * 32];   // 12 KiB
  __shared__ u16 Bs[2][64 * 32];   // 8 KiB

  int ag_off;
  const int ag_base = (64 * wave) * 8;
  {
    int slot = 64 * wave + lane;
    int r = slot >> 2;
    int c = (slot & 3) ^ ((r >> 1) & 3);
    ag_off = r * HDIM + c * 8;
  }
  const int br0 = min(n0 + (tid >> 3), MAXO - 1);
  const int br1 = min(n0 + (tid >> 3) + 32, MAXO - 1);
  const float* bg0 = Bp + (size_t)br0 * HDIM + (tid & 7) * 4;
  const float* bg1 = Bp + (size_t)br1 * HDIM + (tid & 7) * 4;
  int bso[2];
#pragma unroll
  for (int i = 0; i < 2; ++i) {
    int r = (tid >> 3) + 32 * i;
    int c = ((tid & 7) >> 1) ^ ((r >> 1) & 3);
    bso[i] = (r * 4 + c) * 8 + (tid & 1) * 4;
  }
  int a_sl[2], b_sl[2];
#pragma unroll
  for (int m = 0; m < 2; ++m) {
    int r = wr * 32 + m * 16 + lanelo;
    a_sl[m] = (r * 4 + (lanehi ^ ((r >> 1) & 3))) * 8;
    int rb = wc * 32 + m * 16 + lanelo;
    b_sl[m] = (rb * 4 + (lanehi ^ ((rb >> 1) & 3))) * 8;
  }

  f32x4 acc[2][2] = {};
  float4 bA0, bA1, bB0, bB1;
  const int NK = HDIM / 32;  // 96

  auto issue = [&](int kt, float4& r0, float4& r1) {
    const int k2 = kt * 32;
    gll16(Ap + ag_off + k2, &As[kt % 3][ag_base]);
    asm volatile("" ::: "memory");
    r0 = *(const float4*)(bg0 + k2);
    r1 = *(const float4*)(bg1 + k2);
    asm volatile("" ::: "memory");
  };

  auto step = [&](int kt, float4& r0, float4& r1) {
    if (kt + 1 < NK) asm volatile("s_waitcnt vmcnt(3)" ::: "memory");
    else             asm volatile("s_waitcnt vmcnt(0)" ::: "memory");
    {
      u16* bb = &Bs[kt & 1][0];
      uint2 w0, w1v;
      w0.x = (u32)f2b(r0.x) | ((u32)f2b(r0.y) << 16);
      w0.y = (u32)f2b(r0.z) | ((u32)f2b(r0.w) << 16);
      w1v.x = (u32)f2b(r1.x) | ((u32)f2b(r1.y) << 16);
      w1v.y = (u32)f2b(r1.z) | ((u32)f2b(r1.w) << 16);
      *(uint2*)&bb[bso[0]] = w0;
      *(uint2*)&bb[bso[1]] = w1v;
    }
    asm volatile("s_waitcnt lgkmcnt(0)" ::: "memory");
    __builtin_amdgcn_s_barrier();
    asm volatile("" ::: "memory");
    if (kt + 2 < NK) issue(kt + 2, r0, r1);
    const u16* a_ = &As[kt % 3][0];
    const u16* b_ = &Bs[kt & 1][0];
    bf16x8 af[2], bf[2];
#pragma unroll
    for (int m = 0; m < 2; ++m) af[m] = *(const bf16x8*)&a_[a_sl[m]];
#pragma unroll
    for (int n = 0; n < 2; ++n) bf[n] = *(const bf16x8*)&b_[b_sl[n]];
#pragma unroll
    for (int m = 0; m < 2; ++m)
#pragma unroll
      for (int n = 0; n < 2; ++n)
        acc[m][n] = __builtin_amdgcn_mfma_f32_16x16x32_bf16(af[m], bf[n], acc[m][n], 0, 0, 0);
  };

  issue(0, bA0, bA1);
  issue(1, bB0, bB1);
  for (int kt = 0; kt < NK; kt += 2) {
    step(kt, bA0, bA1);
    step(kt + 1, bB0, bB1);
  }

#pragma unroll
  for (int m = 0; m < 2; ++m) {
#pragma unroll
    for (int n = 0; n < 2; ++n) {
      const int col = n0 + wc * 32 + n * 16 + lanelo;
      if (col < odim) {
        const float bias = b2[(size_t)p * MAXO + col];
#pragma unroll
        for (int r = 0; r < 4; ++r) {
          const int row = m0 + wr * 32 + m * 16 + lanehi * 4 + r;
          out[(size_t)row * TOT + off + col] = acc[m][n][r] + bias;
        }
      }
    }
  }
}

extern "C" void kernel_launch(void* const* d_in, const int* in_sizes, int n_in,
                              void* d_out, int out_size, void* d_ws, size_t ws_size,
                              hipStream_t stream) {
  const float* x = (const float*)d_in[0];
  const float* gamma = (const float*)d_in[1];
  const float* beta = (const float*)d_in[2];
  const float* w1 = (const float*)d_in[3];
  const float* w2 = (const float*)d_in[4];
  const float* b2 = (const float*)d_in[5];
  float* out = (float*)d_out;

  u16* xn = (u16*)d_ws;                             // [16][256][768] bf16
  u16* h = (u16*)d_ws + (size_t)NP * NB * DLAT;     // [16][256][3072] bf16

  ln_kernel<<<1024, 256, 0, stream>>>(x, gamma, beta, xn);
  fc1_kernel<<<768, 256, 0, stream>>>(xn, w1, h);
  fc2_kernel<<<NP * 16, 256, 0, stream>>>(h, w2, b2, out);
}